// Round 4
// baseline (1133.913 us; speedup 1.0000x reference)
//
#include <hip/hip_runtime.h>
#include <hip/hip_bf16.h>
#include <math.h>

typedef __hip_bfloat16 bf16;

__device__ __forceinline__ bf16 f2b(float v){ return __float2bfloat16(v); }
__device__ __forceinline__ float ldf(float v){ return v; }
__device__ __forceinline__ float ldf(bf16 v){ return __bfloat162float(v); }

// ---------- conv1: 1->32, 3x3 SAME, relu, maxpool2 -> x1 bf16 [Bs][32][128][128]
__global__ void k_conv1(const float* __restrict__ img, const float* __restrict__ w,
                        const float* __restrict__ bias, bf16* __restrict__ out){
  int idx = blockIdx.x*256 + threadIdx.x;
  int ox = idx & 127, oy = (idx>>7)&127, oc = (idx>>14)&31, b = idx>>19;
  float W[9];
  #pragma unroll
  for(int i=0;i<9;i++) W[i] = w[oc*9+i];
  float bs = bias[oc];
  const float* ip = img + (size_t)b*65536;
  int y0 = oy*2-1, x0 = ox*2-1;
  float patch[4][4];
  #pragma unroll
  for(int py=0;py<4;py++){
    int y=y0+py; bool yok = (unsigned)y<256u;
    #pragma unroll
    for(int px=0;px<4;px++){
      int x=x0+px;
      patch[py][px] = (yok && (unsigned)x<256u) ? ip[y*256+x] : 0.f;
    }
  }
  float best = 0.f;
  #pragma unroll
  for(int py=0;py<2;py++)
  #pragma unroll
  for(int px=0;px<2;px++){
    float a = bs;
    #pragma unroll
    for(int ky=0;ky<3;ky++)
    #pragma unroll
    for(int kx=0;kx<3;kx++)
      a = fmaf(W[ky*3+kx], patch[py+ky][px+kx], a);
    best = fmaxf(best, a);
  }
  out[idx] = f2b(best);
}

// ---------- generic conv 3x3 SAME + relu + maxpool2, 4 out-channels/thread
template<typename TIN, int IC, int OCG, int S>
__global__ void k_conv_pool(const TIN* __restrict__ in, const float* __restrict__ w,
                            const float* __restrict__ bias, float* __restrict__ out){
  __shared__ float Wl[4*IC*9];
  __shared__ float Bl[4];
  int tid = threadIdx.x;
  int idx = blockIdx.x*256 + tid;
  int ox = idx % S, oy = (idx/S)%S;
  int og = (idx/(S*S)) % OCG;        // uniform per block (S*S multiple of 256)
  int b  = idx/(S*S*OCG);
  for(int t = tid; t < 4*IC*9; t += 256) Wl[t] = w[og*4*IC*9 + t];
  if(tid < 4) Bl[tid] = bias[og*4+tid];
  __syncthreads();
  float acc[4][2][2];
  #pragma unroll
  for(int j=0;j<4;j++){
    float bv = Bl[j];
    acc[j][0][0]=bv; acc[j][0][1]=bv; acc[j][1][0]=bv; acc[j][1][1]=bv;
  }
  const int IS = 2*S;
  const TIN* ip = in + (size_t)b*IC*IS*IS;
  int y0 = oy*2-1, x0 = ox*2-1;
  for(int ic=0; ic<IC; ic++){
    float patch[4][4];
    const TIN* cp = ip + (size_t)ic*IS*IS;
    #pragma unroll
    for(int py=0;py<4;py++){
      int y=y0+py; bool yok=(unsigned)y<(unsigned)IS;
      #pragma unroll
      for(int px=0;px<4;px++){
        int x=x0+px;
        patch[py][px] = (yok && (unsigned)x<(unsigned)IS) ? ldf(cp[y*IS+x]) : 0.f;
      }
    }
    #pragma unroll
    for(int j=0;j<4;j++){
      const float* wj = &Wl[(j*IC+ic)*9];
      #pragma unroll
      for(int py=0;py<2;py++)
      #pragma unroll
      for(int px=0;px<2;px++){
        float a = acc[j][py][px];
        #pragma unroll
        for(int ky=0;ky<3;ky++)
        #pragma unroll
        for(int kx=0;kx<3;kx++)
          a = fmaf(wj[ky*3+kx], patch[py+ky][px+kx], a);
        acc[j][py][px] = a;
      }
    }
  }
  #pragma unroll
  for(int j=0;j<4;j++){
    float best = 0.f;
    #pragma unroll
    for(int py=0;py<2;py++)
    #pragma unroll
    for(int px=0;px<2;px++) best = fmaxf(best, acc[j][py][px]);
    out[((size_t)((b*OCG + og)*4 + j)*S + oy)*S + ox] = best;
  }
}

// ---------- conv4: 3x3 SAME + relu, no pool, 32x32, 4 oc/thread
template<int IC, int OCG>
__global__ void k_conv_nopool(const float* __restrict__ in, const float* __restrict__ w,
                              const float* __restrict__ bias, float* __restrict__ out){
  __shared__ float Wl[4*IC*9];
  __shared__ float Bl[4];
  int tid = threadIdx.x;
  int idx = blockIdx.x*256 + tid;
  int x = idx & 31, y = (idx>>5)&31;
  int og = (idx>>10) % OCG;
  int b  = idx/(1024*OCG);
  for(int t=tid; t<4*IC*9; t+=256) Wl[t] = w[og*4*IC*9 + t];
  if(tid<4) Bl[tid] = bias[og*4+tid];
  __syncthreads();
  float acc[4] = {Bl[0], Bl[1], Bl[2], Bl[3]};
  const float* ip = in + (size_t)b*IC*1024;
  for(int ic=0; ic<IC; ic++){
    const float* cp = ip + ic*1024;
    float patch[3][3];
    #pragma unroll
    for(int ky=0;ky<3;ky++){
      int yy = y+ky-1; bool yok=(unsigned)yy<32u;
      #pragma unroll
      for(int kx=0;kx<3;kx++){
        int xx = x+kx-1;
        patch[ky][kx] = (yok && (unsigned)xx<32u) ? cp[yy*32+xx] : 0.f;
      }
    }
    #pragma unroll
    for(int j=0;j<4;j++){
      const float* wj = &Wl[(j*IC+ic)*9];
      #pragma unroll
      for(int ky=0;ky<3;ky++)
      #pragma unroll
      for(int kx=0;kx<3;kx++)
        acc[j] = fmaf(wj[ky*3+kx], patch[ky][kx], acc[j]);
    }
  }
  #pragma unroll
  for(int j=0;j<4;j++)
    out[((size_t)(b*OCG+og)*4+j)*1024 + y*32 + x] = fmaxf(acc[j], 0.f);
}

// ---------- global mean over 1024 px, one block per (b_local, oc)
__global__ void k_mean(const float* __restrict__ x, float* __restrict__ feat){
  __shared__ float red[256];
  int tid = threadIdx.x;
  const float* p = x + (size_t)blockIdx.x*1024;
  red[tid] = p[tid] + p[tid+256] + p[tid+512] + p[tid+768];
  __syncthreads();
  for(int o=128;o>0;o>>=1){ if(tid<o) red[tid]+=red[tid+o]; __syncthreads(); }
  if(tid==0) feat[blockIdx.x] = red[0] * (1.f/1024.f);
}

// ---------- generic linear (torch Linear: w [OUT,IN]), optional relu, f32 out
__global__ void k_lin(const float* __restrict__ x, const float* __restrict__ w,
                      const float* __restrict__ bias, float* __restrict__ y,
                      int IN, int OUT, int RELU){
  int idx = blockIdx.x*256+threadIdx.x;
  if(idx >= 16*OUT) return;
  int o = idx % OUT, b = idx / OUT;
  const float* xp = x + b*IN;
  const float* wp = w + (size_t)o*IN;
  float a = bias[o];
  for(int i=0;i<IN;i++) a = fmaf(xp[i], wp[i], a);
  if(RELU) a = fmaxf(a, 0.f);
  y[idx] = a;
}

// ---------- cosine normalize coords
__global__ void k_norm(const float* __restrict__ c, float* __restrict__ cn){
  int idx = blockIdx.x*256+threadIdx.x;
  if(idx >= 16*350) return;
  float x = c[idx*2], y = c[idx*2+1];
  float n = sqrtf(x*x + y*y);
  float d = fmaxf(n, 1e-12f);
  cn[idx*2] = x/d; cn[idx*2+1] = y/d;
}

// ---------- node mask counts, dtype auto-detected (prefix mask, mask[0]==1 always)
__device__ int mask_mode(const void* p){
  unsigned w0 = ((const unsigned*)p)[0];
  unsigned w1 = ((const unsigned*)p)[1];
  if(w0 == 1u) return (w1 == 0u) ? 4 : 0;       // i64 : i32
  if(w0 == 0x3F800000u) return 3;                // f32
  unsigned short h0 = (unsigned short)(w0 & 0xFFFFu);
  if(h0 == 0x3F80u || h0 == 0x3C00u) return 2;   // bf16 / f16
  return 1;                                      // bytes
}
__device__ int mask_get(const void* p, int i, int mode){
  switch(mode){
    case 0: return ((const int*)p)[i] != 0;
    case 1: return ((const unsigned char*)p)[i] != 0;
    case 2: return ((const unsigned short*)p)[i] != 0;
    case 3: return ((const float*)p)[i] != 0.f;
    default: return ((const long long*)p)[i] != 0ll;
  }
}
__global__ void k_counts(const void* __restrict__ masks, int* __restrict__ counts){
  int b = blockIdx.x, tid = threadIdx.x;
  int mode = mask_mode(masks);
  int c = 0;
  for(int i=tid; i<350; i+=64) c += mask_get(masks, b*350+i, mode);
  for(int o=32;o>0;o>>=1) c += __shfl_down(c, o);
  if(tid==0) counts[b] = c;
}

// ---------- pairwise: sim -> 1->32->16->1 MLP -> sigmoid -> mask (f32 out)
__global__ void k_adj(const float* __restrict__ cn, const int* __restrict__ counts,
                      const float* __restrict__ w1, const float* __restrict__ b1,
                      const float* __restrict__ w2, const float* __restrict__ b2,
                      const float* __restrict__ w3, const float* __restrict__ b3,
                      float* __restrict__ out){
  __shared__ float W1[32], B1[32], W2[512], B2[16], W3[16], B3;
  int tid = threadIdx.x;
  if(tid<32){ W1[tid]=w1[tid]; B1[tid]=b1[tid]; }
  for(int t=tid; t<512; t+=256) W2[t]=w2[t];
  if(tid<16){ B2[tid]=b2[tid]; W3[tid]=w3[tid]; }
  if(tid==0) B3=b3[0];
  __syncthreads();
  int idx = blockIdx.x*256+tid;
  if(idx >= 16*350*350) return;
  int m  = idx % 350;
  int t2 = idx / 350;
  int n  = t2 % 350;
  int b  = t2 / 350;
  int cnt = counts[b];
  float o = 0.f;
  if(cnt > 1 && n < cnt && m < cnt){
    float xn = cn[(b*350+n)*2], yn = cn[(b*350+n)*2+1];
    float xm = cn[(b*350+m)*2], ym = cn[(b*350+m)*2+1];
    float s = xn*xm + yn*ym;
    float h1[32];
    #pragma unroll
    for(int k=0;k<32;k++) h1[k] = fmaxf(fmaf(s, W1[k], B1[k]), 0.f);
    float a3 = B3;
    #pragma unroll
    for(int j=0;j<16;j++){
      float t = B2[j];
      #pragma unroll
      for(int k=0;k<32;k++) t = fmaf(h1[k], W2[j*32+k], t);
      a3 = fmaf(fmaxf(t,0.f), W3[j], a3);
    }
    o = 1.f/(1.f + expf(-a3));
  }
  out[idx] = o;
}

extern "C" void kernel_launch(void* const* d_in, const int* in_sizes, int n_in,
                              void* d_out, int out_size, void* d_ws, size_t ws_size,
                              hipStream_t stream){
  const float* images = (const float*)d_in[0];
  const void*  masks  = d_in[1];
  const float *c1w=(const float*)d_in[2],  *c1b=(const float*)d_in[3];
  const float *c2w=(const float*)d_in[4],  *c2b=(const float*)d_in[5];
  const float *c3w=(const float*)d_in[6],  *c3b=(const float*)d_in[7];
  const float *c4w=(const float*)d_in[8],  *c4b=(const float*)d_in[9];
  const float *nd1w=(const float*)d_in[10],*nd1b=(const float*)d_in[11];
  const float *nd2w=(const float*)d_in[12],*nd2b=(const float*)d_in[13];
  const float *cp1w=(const float*)d_in[14],*cp1b=(const float*)d_in[15];
  const float *cp2w=(const float*)d_in[16],*cp2b=(const float*)d_in[17];
  const float *mc1w=(const float*)d_in[18],*mc1b=(const float*)d_in[19];
  const float *mc2w=(const float*)d_in[20],*mc2b=(const float*)d_in[21];
  const float *mc3w=(const float*)d_in[22],*mc3b=(const float*)d_in[23];
  float* out = (float*)d_out;   // f32 outputs: coords[11200] | adjacency[1960000] | count[16]

  // ---- workspace: small tail buffers first, then two conv ping-pong regions
  char* W = (char*)d_ws;
  float* feat   = (float*)W;                  // 4096 f32
  float* h512   = feat + 4096;                // 8192
  float* cn     = h512 + 8192;                // 11200
  float* h256   = cn + 11200;                 // 4096
  int*   counts = (int*)(h256 + 4096);        // 16
  const size_t TAIL = 262144;                 // 256 KB

  int Bs = 16;                                // images per slice
  while (Bs > 1 && TAIL + (size_t)2*Bs*1048576 > ws_size) Bs >>= 1;

  char* RA = W + TAIL;                        // region A: Bs MB
  char* RB = RA + (size_t)Bs*1048576;         // region B: Bs MB
  bf16*  x1 = (bf16*)RA;                      // [Bs][32][128][128] bf16 (Bs MB)
  float* x2 = (float*)RB;                     // [Bs][64][64][64]   f32  (Bs MB)
  float* x3 = (float*)RA;                     // [Bs][128][32][32]  f32  (Bs/2 MB)
  float* x4 = (float*)RB;                     // [Bs][256][32][32]  f32  (Bs MB)

  for (int b0 = 0; b0 < 16; b0 += Bs){
    k_conv1<<<Bs*2048, 256, 0, stream>>>(images + (size_t)b0*65536, c1w, c1b, x1);
    k_conv_pool<bf16, 32, 16, 64><<<Bs*256, 256, 0, stream>>>(x1, c2w, c2b, x2);
    k_conv_pool<float, 64, 32, 32><<<Bs*128, 256, 0, stream>>>(x2, c3w, c3b, x3);
    k_conv_nopool<128, 64><<<Bs*256, 256, 0, stream>>>(x3, c4w, c4b, x4);
    k_mean<<<Bs*256, 256, 0, stream>>>(x4, feat + b0*256);
  }

  float* coordsOut = out;                 // [16][350][2]
  float* adjOut    = out + 11200;         // [16][350][350]
  float* countOut  = out + 11200 + 1960000; // [16]

  k_lin<<<(16*512+255)/256, 256, 0, stream>>>(feat, nd1w, nd1b, h512, 256, 512, 1);
  k_lin<<<(16*700+255)/256, 256, 0, stream>>>(h512, nd2w, nd2b, coordsOut, 512, 700, 0);
  k_lin<<<(16*256+255)/256, 256, 0, stream>>>(feat, cp1w, cp1b, h256, 256, 256, 1);
  k_lin<<<1, 256, 0, stream>>>(h256, cp2w, cp2b, countOut, 256, 1, 0);

  k_norm<<<(5600+255)/256, 256, 0, stream>>>(coordsOut, cn);
  k_counts<<<16, 64, 0, stream>>>(masks, counts);
  k_adj<<<(1960000+255)/256, 256, 0, stream>>>(cn, counts, mc1w, mc1b, mc2w, mc2b,
                                               mc3w, mc3b, adjOut);
}

// Round 5
// 289.272 us; speedup vs baseline: 3.9199x; 3.9199x over previous
//
#include <hip/hip_runtime.h>
#include <hip/hip_bf16.h>
#include <math.h>

typedef __hip_bfloat16 bf16;
typedef __attribute__((ext_vector_type(8))) short short8;
typedef __attribute__((ext_vector_type(4))) float f32x4;

__device__ __forceinline__ bf16 f2b(float v){ return __float2bfloat16(v); }
__device__ __forceinline__ float ldf(float v){ return v; }
__device__ __forceinline__ float ldf(bf16 v){ return __bfloat162float(v); }
__device__ __forceinline__ unsigned short fbits(float v){
  __hip_bfloat16 h = __float2bfloat16(v);
  return *reinterpret_cast<unsigned short*>(&h);
}

// ---------- zero a float buffer
__global__ void k_zero(float* __restrict__ p, int n){
  int i = blockIdx.x*256 + threadIdx.x;
  if(i < n) p[i] = 0.f;
}

// ---------- weight transform: [OC][IC][3][3] f32 -> [tap][OC][IC] bf16
__global__ void k_wtrans(const float* __restrict__ w, bf16* __restrict__ wt,
                         int OC, int IC){
  int idx = blockIdx.x*256 + threadIdx.x;
  if(idx >= OC*IC*9) return;
  int ic = idx % IC; int t2 = idx / IC; int oc = t2 % OC; int tap = t2 / OC;
  wt[idx] = f2b(w[(oc*IC + ic)*9 + tap]);
}

// ---------- conv1: 1->32, 3x3 SAME, relu, maxpool2 -> channels-last bf16 [16][128][128][32]
__global__ __launch_bounds__(256) void k_conv1(const float* __restrict__ img,
                        const float* __restrict__ w, const float* __restrict__ bias,
                        bf16* __restrict__ out){
  __shared__ float Wl[288], Bl[32];
  int tid = threadIdx.x;
  for(int t=tid; t<288; t+=256) Wl[t] = w[t];
  if(tid<32) Bl[tid] = bias[tid];
  __syncthreads();
  int idx = blockIdx.x*256 + tid;
  int ox = idx & 127, oy = (idx>>7)&127, b = idx>>14;
  const float* ip = img + (size_t)b*65536;
  int y0 = oy*2-1, x0 = ox*2-1;
  float patch[4][4];
  #pragma unroll
  for(int py=0;py<4;py++){
    int y=y0+py; bool yok = (unsigned)y<256u;
    #pragma unroll
    for(int px=0;px<4;px++){
      int x=x0+px;
      patch[py][px] = (yok && (unsigned)x<256u) ? ip[y*256+x] : 0.f;
    }
  }
  unsigned u[16];
  #pragma unroll
  for(int og=0; og<16; og++){
    unsigned short hb[2];
    #pragma unroll
    for(int h=0; h<2; h++){
      int oc = og*2 + h;
      const float* wj = &Wl[oc*9];
      float best = 0.f;
      #pragma unroll
      for(int py=0;py<2;py++)
      #pragma unroll
      for(int px=0;px<2;px++){
        float a = Bl[oc];
        #pragma unroll
        for(int ky=0;ky<3;ky++)
        #pragma unroll
        for(int kx=0;kx<3;kx++)
          a = fmaf(wj[ky*3+kx], patch[py+ky][px+kx], a);
        best = fmaxf(best, a);
      }
      hb[h] = fbits(best);
    }
    u[og] = (unsigned)hb[0] | ((unsigned)hb[1] << 16);
  }
  uint4* dst = (uint4*)(out + (size_t)idx*32);
  dst[0] = make_uint4(u[0],u[1],u[2],u[3]);
  dst[1] = make_uint4(u[4],u[5],u[6],u[7]);
  dst[2] = make_uint4(u[8],u[9],u[10],u[11]);
  dst[3] = make_uint4(u[12],u[13],u[14],u[15]);
}

// ---------- MFMA tap-loop implicit-GEMM conv, channels-last bf16 in/out
// L=2: 32->64  @128, pool.  L=3: 64->128 @64, pool.  L=4: 128->256 @32, no pool.
template<int L>
__global__ __launch_bounds__(256) void k_convmfma(const bf16* __restrict__ in,
                      const bf16* __restrict__ wt, const float* __restrict__ bias,
                      bf16* __restrict__ out){
  constexpr int IC   = L==2?32:(L==3?64:128);
  constexpr int OC   = L==2?64:(L==3?128:256);
  constexpr int HW   = L==2?128:(L==3?64:32);
  constexpr int POOL = L==4?0:1;
  constexpr int WNF  = L==4?2:4;        // N-frags per wave
  constexpr int IC8  = IC/8;
  constexpr int SM   = (IC8-1)&7;       // swizzle mask
  constexpr int KC   = IC/32;           // MFMAs per tap (K chunks)
  constexpr int XT   = HW;
  constexpr int ROWC = (XT+2)*IC8;      // 16B chunks per LDS row
  __shared__ short8 T[4*ROWC];

  int bid = blockIdx.x;
  int b, py, bt = 0;
  if(L==4){ b = bid>>5; py = (bid>>1)&15; bt = bid&1; }
  else if(L==3){ b = bid>>5; py = bid&31; }
  else { b = bid>>6; py = bid&63; }

  int tid = threadIdx.x;
  int w = tid>>6, l15 = tid&15, lhi = (tid>>4)&3;

  int mbase, nbase;
  if(L==2){ mbase = w*32; nbase = 0; }
  else if(L==3){ mbase = (w&1)*32; nbase = (w>>1)*64; }
  else { mbase = 0; nbase = bt*128 + w*32; }

  // zero halo columns X=0 and X=XT+1 (all k chunks -> swizzle-proof)
  for(int c=tid; c<4*2*IC8; c+=256){
    int r = c/(2*IC8), rem = c%(2*IC8);
    int X = (rem>=IC8)?(XT+1):0;
    int k = rem%IC8;
    short8 z = {0,0,0,0,0,0,0,0};
    T[(r*(XT+2)+X)*IC8 + k] = z;
  }
  // stage 4 input rows (2*py-1 .. 2*py+2), XOR-swizzled ic8
  for(int c=tid; c<4*XT*IC8; c+=256){
    int r = c/(XT*IC8), rem = c%(XT*IC8);
    int x = rem/IC8, k = rem%IC8;
    int gy = 2*py - 1 + r;
    short8 v = {0,0,0,0,0,0,0,0};
    if((unsigned)gy < (unsigned)HW)
      v = *(const short8*)(in + (((size_t)b*HW + gy)*XT + x)*IC + k*8);
    int X = x+1;
    T[(r*(XT+2)+X)*IC8 + (k ^ (X&SM))] = v;
  }
  __syncthreads();

  float bv[WNF];
  #pragma unroll
  for(int n=0;n<WNF;n++) bv[n] = bias[nbase + n*16 + l15];
  f32x4 acc[2][2][WNF];
  #pragma unroll
  for(int r=0;r<2;r++)
  #pragma unroll
  for(int m=0;m<2;m++)
  #pragma unroll
  for(int n=0;n<WNF;n++){
    acc[r][m][n][0]=bv[n]; acc[r][m][n][1]=bv[n];
    acc[r][m][n][2]=bv[n]; acc[r][m][n][3]=bv[n];
  }

  const short8* wt8 = (const short8*)wt;
  #pragma unroll
  for(int tap=0; tap<9; tap++){
    const int dy = tap/3 - 1, dx = tap%3 - 1;
    #pragma unroll
    for(int kc=0; kc<KC; kc++){
      short8 Bf[WNF];
      #pragma unroll
      for(int n=0;n<WNF;n++){
        int oc = nbase + n*16 + l15;
        Bf[n] = wt8[(size_t)(tap*OC + oc)*IC8 + kc*4 + lhi];
      }
      short8 Af[2][2];
      #pragma unroll
      for(int r=0;r<2;r++)
      #pragma unroll
      for(int m=0;m<2;m++){
        int X = mbase + m*16 + l15 + dx + 1;
        int rs = r + dy + 1;
        Af[r][m] = T[(rs*(XT+2)+X)*IC8 + ((kc*4+lhi) ^ (X&SM))];
      }
      #pragma unroll
      for(int r=0;r<2;r++)
      #pragma unroll
      for(int m=0;m<2;m++)
      #pragma unroll
      for(int n=0;n<WNF;n++)
        acc[r][m][n] = __builtin_amdgcn_mfma_f32_16x16x32_bf16(Af[r][m], Bf[n], acc[r][m][n], 0,0,0);
    }
  }

  if(POOL){
    constexpr int HP = HW/2;
    #pragma unroll
    for(int m=0;m<2;m++)
    #pragma unroll
    for(int n=0;n<WNF;n++){
      int oc = nbase + n*16 + l15;
      #pragma unroll
      for(int t=0;t<2;t++){
        float v = fmaxf(fmaxf(acc[0][m][n][2*t], acc[0][m][n][2*t+1]),
                        fmaxf(acc[1][m][n][2*t], acc[1][m][n][2*t+1]));
        v = fmaxf(v, 0.f);
        int xp = (mbase + m*16)/2 + lhi*2 + t;
        out[(((size_t)b*HP + py)*HP + xp)*OC + oc] = f2b(v);
      }
    }
  } else {
    #pragma unroll
    for(int r=0;r<2;r++)
    #pragma unroll
    for(int m=0;m<2;m++)
    #pragma unroll
    for(int n=0;n<WNF;n++){
      int oc = nbase + n*16 + l15;
      #pragma unroll
      for(int j=0;j<4;j++){
        int y = 2*py + r, x = mbase + m*16 + lhi*4 + j;
        out[(((size_t)b*HW + y)*HW + x)*OC + oc] = f2b(fmaxf(acc[r][m][n][j], 0.f));
      }
    }
  }
}

// ---------- mean over spatial, channels-last bf16 [16][1024][256] -> feat f32 [16][256]
__global__ void k_mean(const bf16* __restrict__ x, float* __restrict__ feat){
  int b = blockIdx.x>>2, q = blockIdx.x&3;
  int oc = threadIdx.x;
  float s = 0.f;
  const bf16* p = x + (((size_t)b*1024) + q*256)*256 + oc;
  for(int i=0;i<256;i++) s += ldf(p[i*256]);
  atomicAdd(&feat[b*256+oc], s*(1.f/1024.f));
}

// ---------- generic linear (torch Linear: w [OUT,IN]), optional relu
__global__ void k_lin(const float* __restrict__ x, const float* __restrict__ w,
                      const float* __restrict__ bias, float* __restrict__ y,
                      int IN, int OUT, int RELU){
  int idx = blockIdx.x*256+threadIdx.x;
  if(idx >= 16*OUT) return;
  int o = idx % OUT, b = idx / OUT;
  const float* xp = x + b*IN;
  const float* wp = w + (size_t)o*IN;
  float a = bias[o];
  for(int i=0;i<IN;i++) a = fmaf(xp[i], wp[i], a);
  if(RELU) a = fmaxf(a, 0.f);
  y[idx] = a;
}

// ---------- cosine normalize coords
__global__ void k_norm(const float* __restrict__ c, float* __restrict__ cn){
  int idx = blockIdx.x*256+threadIdx.x;
  if(idx >= 16*350) return;
  float x = c[idx*2], y = c[idx*2+1];
  float n = sqrtf(x*x + y*y);
  float d = fmaxf(n, 1e-12f);
  cn[idx*2] = x/d; cn[idx*2+1] = y/d;
}

// ---------- node mask counts, dtype auto-detected (prefix mask, mask[0]==1 always)
__device__ int mask_mode(const void* p){
  unsigned w0 = ((const unsigned*)p)[0];
  unsigned w1 = ((const unsigned*)p)[1];
  if(w0 == 1u) return (w1 == 0u) ? 4 : 0;
  if(w0 == 0x3F800000u) return 3;
  unsigned short h0 = (unsigned short)(w0 & 0xFFFFu);
  if(h0 == 0x3F80u || h0 == 0x3C00u) return 2;
  return 1;
}
__device__ int mask_get(const void* p, int i, int mode){
  switch(mode){
    case 0: return ((const int*)p)[i] != 0;
    case 1: return ((const unsigned char*)p)[i] != 0;
    case 2: return ((const unsigned short*)p)[i] != 0;
    case 3: return ((const float*)p)[i] != 0.f;
    default: return ((const long long*)p)[i] != 0ll;
  }
}
__global__ void k_counts(const void* __restrict__ masks, int* __restrict__ counts){
  int b = blockIdx.x, tid = threadIdx.x;
  int mode = mask_mode(masks);
  int c = 0;
  for(int i=tid; i<350; i+=64) c += mask_get(masks, b*350+i, mode);
  for(int o=32;o>0;o>>=1) c += __shfl_down(c, o);
  if(tid==0) counts[b] = c;
}

// ---------- pairwise: sim -> 1->32->16->1 MLP -> sigmoid -> mask (f32 out)
__global__ void k_adj(const float* __restrict__ cn, const int* __restrict__ counts,
                      const float* __restrict__ w1, const float* __restrict__ b1,
                      const float* __restrict__ w2, const float* __restrict__ b2,
                      const float* __restrict__ w3, const float* __restrict__ b3,
                      float* __restrict__ out){
  __shared__ float W1[32], B1[32], W2[512], B2[16], W3[16], B3;
  int tid = threadIdx.x;
  if(tid<32){ W1[tid]=w1[tid]; B1[tid]=b1[tid]; }
  for(int t=tid; t<512; t+=256) W2[t]=w2[t];
  if(tid<16){ B2[tid]=b2[tid]; W3[tid]=w3[tid]; }
  if(tid==0) B3=b3[0];
  __syncthreads();
  int idx = blockIdx.x*256+tid;
  if(idx >= 16*350*350) return;
  int m  = idx % 350;
  int t2 = idx / 350;
  int n  = t2 % 350;
  int b  = t2 / 350;
  int cnt = counts[b];
  float o = 0.f;
  if(cnt > 1 && n < cnt && m < cnt){
    float xn = cn[(b*350+n)*2], yn = cn[(b*350+n)*2+1];
    float xm = cn[(b*350+m)*2], ym = cn[(b*350+m)*2+1];
    float s = xn*xm + yn*ym;
    float h1[32];
    #pragma unroll
    for(int k=0;k<32;k++) h1[k] = fmaxf(fmaf(s, W1[k], B1[k]), 0.f);
    float a3 = B3;
    #pragma unroll
    for(int j=0;j<16;j++){
      float t = B2[j];
      #pragma unroll
      for(int k=0;k<32;k++) t = fmaf(h1[k], W2[j*32+k], t);
      a3 = fmaf(fmaxf(t,0.f), W3[j], a3);
    }
    o = 1.f/(1.f + expf(-a3));
  }
  out[idx] = o;
}

extern "C" void kernel_launch(void* const* d_in, const int* in_sizes, int n_in,
                              void* d_out, int out_size, void* d_ws, size_t ws_size,
                              hipStream_t stream){
  const float* images = (const float*)d_in[0];
  const void*  masks  = d_in[1];
  const float *c1w=(const float*)d_in[2],  *c1b=(const float*)d_in[3];
  const float *c2w=(const float*)d_in[4],  *c2b=(const float*)d_in[5];
  const float *c3w=(const float*)d_in[6],  *c3b=(const float*)d_in[7];
  const float *c4w=(const float*)d_in[8],  *c4b=(const float*)d_in[9];
  const float *nd1w=(const float*)d_in[10],*nd1b=(const float*)d_in[11];
  const float *nd2w=(const float*)d_in[12],*nd2b=(const float*)d_in[13];
  const float *cp1w=(const float*)d_in[14],*cp1b=(const float*)d_in[15];
  const float *cp2w=(const float*)d_in[16],*cp2b=(const float*)d_in[17];
  const float *mc1w=(const float*)d_in[18],*mc1b=(const float*)d_in[19];
  const float *mc2w=(const float*)d_in[20],*mc2b=(const float*)d_in[21];
  const float *mc3w=(const float*)d_in[22],*mc3b=(const float*)d_in[23];
  float* out = (float*)d_out;   // f32: coords[11200] | adjacency[1960000] | count[16]

  // ---- workspace
  char* W = (char*)d_ws;
  float* feat   = (float*)W;                    // 4096 f32
  float* h512   = feat + 4096;                  // 8192
  float* cn     = h512 + 8192;                  // 11200
  float* h256   = cn + 11200;                   // 4096
  int*   counts = (int*)(h256 + 4096);          // 16
  bf16*  wt2 = (bf16*)(W + 98304);              // 9*64*32   = 18432  bf16
  bf16*  wt3 = (bf16*)(W + 135168);             // 9*128*64  = 73728
  bf16*  wt4 = (bf16*)(W + 282624);             // 9*256*128 = 294912
  bf16*  x1 = (bf16*)(W + 1048576);             // [16][128][128][32]  16.78 MB (region A)
  bf16*  x2 = (bf16*)(W + 1048576 + 16777216);  // [16][64][64][64]    8.39 MB (region B)
  bf16*  x3 = (bf16*)(W + 1048576);             // [16][32][32][128]   4.19 MB (region A reuse)
  bf16*  x4 = (bf16*)(W + 1048576 + 16777216);  // [16][32][32][256]   8.39 MB (region B reuse)

  k_zero<<<16, 256, 0, stream>>>(feat, 4096);
  k_wtrans<<<72, 256, 0, stream>>>(c2w, wt2, 64, 32);
  k_wtrans<<<288, 256, 0, stream>>>(c3w, wt3, 128, 64);
  k_wtrans<<<1152, 256, 0, stream>>>(c4w, wt4, 256, 128);

  k_conv1<<<1024, 256, 0, stream>>>(images, c1w, c1b, x1);
  k_convmfma<2><<<1024, 256, 0, stream>>>(x1, wt2, c2b, x2);
  k_convmfma<3><<<512, 256, 0, stream>>>(x2, wt3, c3b, x3);
  k_convmfma<4><<<512, 256, 0, stream>>>(x3, wt4, c4b, x4);
  k_mean<<<64, 256, 0, stream>>>(x4, feat);

  float* coordsOut = out;
  float* adjOut    = out + 11200;
  float* countOut  = out + 11200 + 1960000;

  k_lin<<<(16*512+255)/256, 256, 0, stream>>>(feat, nd1w, nd1b, h512, 256, 512, 1);
  k_lin<<<(16*700+255)/256, 256, 0, stream>>>(h512, nd2w, nd2b, coordsOut, 512, 700, 0);
  k_lin<<<(16*256+255)/256, 256, 0, stream>>>(feat, cp1w, cp1b, h256, 256, 256, 1);
  k_lin<<<1, 256, 0, stream>>>(h256, cp2w, cp2b, countOut, 256, 1, 0);

  k_norm<<<(5600+255)/256, 256, 0, stream>>>(coordsOut, cn);
  k_counts<<<16, 64, 0, stream>>>(masks, counts);
  k_adj<<<(1960000+255)/256, 256, 0, stream>>>(cn, counts, mc1w, mc1b, mc2w, mc2b,
                                               mc3w, mc3b, adjOut);
}

// Round 6
// 136.847 us; speedup vs baseline: 8.2860x; 2.1138x over previous
//
#include <hip/hip_runtime.h>
#include <hip/hip_bf16.h>
#include <math.h>

typedef __hip_bfloat16 bf16;
typedef __attribute__((ext_vector_type(8))) short short8;
typedef __attribute__((ext_vector_type(4))) float f32x4;

__device__ __forceinline__ bf16 f2b(float v){ return __float2bfloat16(v); }
__device__ __forceinline__ float ldf(float v){ return v; }
__device__ __forceinline__ float ldf(bf16 v){ return __bfloat162float(v); }
__device__ __forceinline__ unsigned short fbits(float v){
  __hip_bfloat16 h = __float2bfloat16(v);
  return *reinterpret_cast<unsigned short*>(&h);
}

// ---------- weight transform: [OC][IC][3][3] f32 -> [tap][OC][IC] bf16
__global__ void k_wtrans(const float* __restrict__ w, bf16* __restrict__ wt,
                         int OC, int IC){
  int idx = blockIdx.x*256 + threadIdx.x;
  if(idx >= OC*IC*9) return;
  int ic = idx % IC; int t2 = idx / IC; int oc = t2 % OC; int tap = t2 / OC;
  wt[idx] = f2b(w[(oc*IC + ic)*9 + tap]);
}

// ---------- conv1: 1->32, 3x3 SAME, relu, maxpool2 -> channels-last bf16 [16][128][128][32]
__global__ __launch_bounds__(256) void k_conv1(const float* __restrict__ img,
                        const float* __restrict__ w, const float* __restrict__ bias,
                        bf16* __restrict__ out){
  __shared__ float Wl[288], Bl[32];
  int tid = threadIdx.x;
  for(int t=tid; t<288; t+=256) Wl[t] = w[t];
  if(tid<32) Bl[tid] = bias[tid];
  __syncthreads();
  int idx = blockIdx.x*256 + tid;
  int ox = idx & 127, oy = (idx>>7)&127, b = idx>>14;
  const float* ip = img + (size_t)b*65536;
  int y0 = oy*2-1, x0 = ox*2-1;
  float patch[4][4];
  #pragma unroll
  for(int py=0;py<4;py++){
    int y=y0+py; bool yok = (unsigned)y<256u;
    #pragma unroll
    for(int px=0;px<4;px++){
      int x=x0+px;
      patch[py][px] = (yok && (unsigned)x<256u) ? ip[y*256+x] : 0.f;
    }
  }
  unsigned u[16];
  #pragma unroll
  for(int og=0; og<16; og++){
    unsigned short hb[2];
    #pragma unroll
    for(int h=0; h<2; h++){
      int oc = og*2 + h;
      const float* wj = &Wl[oc*9];
      float best = 0.f;
      #pragma unroll
      for(int py=0;py<2;py++)
      #pragma unroll
      for(int px=0;px<2;px++){
        float a = Bl[oc];
        #pragma unroll
        for(int ky=0;ky<3;ky++)
        #pragma unroll
        for(int kx=0;kx<3;kx++)
          a = fmaf(wj[ky*3+kx], patch[py+ky][px+kx], a);
        best = fmaxf(best, a);
      }
      hb[h] = fbits(best);
    }
    u[og] = (unsigned)hb[0] | ((unsigned)hb[1] << 16);
  }
  uint4* dst = (uint4*)(out + (size_t)idx*32);
  dst[0] = make_uint4(u[0],u[1],u[2],u[3]);
  dst[1] = make_uint4(u[4],u[5],u[6],u[7]);
  dst[2] = make_uint4(u[8],u[9],u[10],u[11]);
  dst[3] = make_uint4(u[12],u[13],u[14],u[15]);
}

// ---------- MFMA tap-loop implicit-GEMM conv, channels-last bf16 in/out
template<int L>
__global__ __launch_bounds__(256) void k_convmfma(const bf16* __restrict__ in,
                      const bf16* __restrict__ wt, const float* __restrict__ bias,
                      bf16* __restrict__ out){
  constexpr int IC   = L==2?32:(L==3?64:128);
  constexpr int OC   = L==2?64:(L==3?128:256);
  constexpr int HW   = L==2?128:(L==3?64:32);
  constexpr int POOL = L==4?0:1;
  constexpr int WNF  = L==4?2:4;        // N-frags per wave
  constexpr int IC8  = IC/8;
  constexpr int SM   = (IC8-1)&7;       // swizzle mask
  constexpr int KC   = IC/32;           // MFMAs per tap (K chunks)
  constexpr int XT   = HW;
  constexpr int ROWC = (XT+2)*IC8;      // 16B chunks per LDS row
  __shared__ short8 T[4*ROWC];

  int bid = blockIdx.x;
  int b, py, bt = 0;
  if(L==4){ b = bid>>5; py = (bid>>1)&15; bt = bid&1; }
  else if(L==3){ b = bid>>5; py = bid&31; }
  else { b = bid>>6; py = bid&63; }

  int tid = threadIdx.x;
  int w = tid>>6, l15 = tid&15, lhi = (tid>>4)&3;

  int mbase, nbase;
  if(L==2){ mbase = w*32; nbase = 0; }
  else if(L==3){ mbase = (w&1)*32; nbase = (w>>1)*64; }
  else { mbase = 0; nbase = bt*128 + w*32; }

  // zero halo columns X=0 and X=XT+1
  for(int c=tid; c<4*2*IC8; c+=256){
    int r = c/(2*IC8), rem = c%(2*IC8);
    int X = (rem>=IC8)?(XT+1):0;
    int k = rem%IC8;
    short8 z = {0,0,0,0,0,0,0,0};
    T[(r*(XT+2)+X)*IC8 + k] = z;
  }
  // stage 4 input rows (2*py-1 .. 2*py+2), XOR-swizzled ic8
  for(int c=tid; c<4*XT*IC8; c+=256){
    int r = c/(XT*IC8), rem = c%(XT*IC8);
    int x = rem/IC8, k = rem%IC8;
    int gy = 2*py - 1 + r;
    short8 v = {0,0,0,0,0,0,0,0};
    if((unsigned)gy < (unsigned)HW)
      v = *(const short8*)(in + (((size_t)b*HW + gy)*XT + x)*IC + k*8);
    int X = x+1;
    T[(r*(XT+2)+X)*IC8 + (k ^ (X&SM))] = v;
  }
  __syncthreads();

  float bv[WNF];
  #pragma unroll
  for(int n=0;n<WNF;n++) bv[n] = bias[nbase + n*16 + l15];
  f32x4 acc[2][2][WNF];
  #pragma unroll
  for(int r=0;r<2;r++)
  #pragma unroll
  for(int m=0;m<2;m++)
  #pragma unroll
  for(int n=0;n<WNF;n++){
    acc[r][m][n][0]=bv[n]; acc[r][m][n][1]=bv[n];
    acc[r][m][n][2]=bv[n]; acc[r][m][n][3]=bv[n];
  }

  const short8* wt8 = (const short8*)wt;
  #pragma unroll
  for(int tap=0; tap<9; tap++){
    const int dy = tap/3 - 1, dx = tap%3 - 1;
    #pragma unroll
    for(int kc=0; kc<KC; kc++){
      short8 Bf[WNF];
      #pragma unroll
      for(int n=0;n<WNF;n++){
        int oc = nbase + n*16 + l15;
        Bf[n] = wt8[(size_t)(tap*OC + oc)*IC8 + kc*4 + lhi];
      }
      short8 Af[2][2];
      #pragma unroll
      for(int r=0;r<2;r++)
      #pragma unroll
      for(int m=0;m<2;m++){
        int X = mbase + m*16 + l15 + dx + 1;
        int rs = r + dy + 1;
        Af[r][m] = T[(rs*(XT+2)+X)*IC8 + ((kc*4+lhi) ^ (X&SM))];
      }
      #pragma unroll
      for(int r=0;r<2;r++)
      #pragma unroll
      for(int m=0;m<2;m++)
      #pragma unroll
      for(int n=0;n<WNF;n++)
        acc[r][m][n] = __builtin_amdgcn_mfma_f32_16x16x32_bf16(Af[r][m], Bf[n], acc[r][m][n], 0,0,0);
    }
  }

  if(POOL){
    constexpr int HP = HW/2;
    #pragma unroll
    for(int m=0;m<2;m++)
    #pragma unroll
    for(int n=0;n<WNF;n++){
      int oc = nbase + n*16 + l15;
      #pragma unroll
      for(int t=0;t<2;t++){
        float v = fmaxf(fmaxf(acc[0][m][n][2*t], acc[0][m][n][2*t+1]),
                        fmaxf(acc[1][m][n][2*t], acc[1][m][n][2*t+1]));
        v = fmaxf(v, 0.f);
        int xp = (mbase + m*16)/2 + lhi*2 + t;
        out[(((size_t)b*HP + py)*HP + xp)*OC + oc] = f2b(v);
      }
    }
  } else {
    #pragma unroll
    for(int r=0;r<2;r++)
    #pragma unroll
    for(int m=0;m<2;m++)
    #pragma unroll
    for(int n=0;n<WNF;n++){
      int oc = nbase + n*16 + l15;
      #pragma unroll
      for(int j=0;j<4;j++){
        int y = 2*py + r, x = mbase + m*16 + lhi*4 + j;
        out[(((size_t)b*HW + y)*HW + x)*OC + oc] = f2b(fmaxf(acc[r][m][n][j], 0.f));
      }
    }
  }
}

// ---------- mean stage 1: [16][1024][256] bf16 -> partial [16*16][256] f32
__global__ void k_mean1(const bf16* __restrict__ x, float* __restrict__ partial){
  int blk = blockIdx.x;            // b*16 + q
  int b = blk>>4, q = blk&15;
  int oc = threadIdx.x;
  float s = 0.f;
  const bf16* p = x + (((size_t)b*1024) + q*64)*256 + oc;
  for(int i=0;i<64;i++) s += ldf(p[i*256]);
  partial[blk*256 + oc] = s;
}
// ---------- mean stage 2: deterministic final reduce
__global__ void k_mean2(const float* __restrict__ partial, float* __restrict__ feat){
  int b = blockIdx.x, oc = threadIdx.x;
  float s = 0.f;
  #pragma unroll
  for(int q=0;q<16;q++) s += partial[(b*16+q)*256 + oc];
  feat[b*256+oc] = s*(1.f/1024.f);
}

// ---------- linear: one wave per output element, lanes partition IN (float4, coalesced)
template<int IN>
__global__ __launch_bounds__(256) void k_linw(const float* __restrict__ x,
                      const float* __restrict__ w, const float* __restrict__ bias,
                      float* __restrict__ y, int OUT, int RELU){
  int gw = (blockIdx.x*256 + threadIdx.x)>>6;
  int lane = threadIdx.x & 63;
  if(gw >= 16*OUT) return;
  int o = gw % OUT, b = gw / OUT;
  const float4* xp = (const float4*)(x + b*IN);
  const float4* wp = (const float4*)(w + (size_t)o*IN);
  float a = 0.f;
  #pragma unroll
  for(int i=lane; i<IN/4; i+=64){
    float4 xv = xp[i], wv = wp[i];
    a = fmaf(xv.x, wv.x, a); a = fmaf(xv.y, wv.y, a);
    a = fmaf(xv.z, wv.z, a); a = fmaf(xv.w, wv.w, a);
  }
  #pragma unroll
  for(int off=32; off>0; off>>=1) a += __shfl_xor(a, off);
  if(lane==0){
    a += bias[o];
    if(RELU) a = fmaxf(a, 0.f);
    y[gw] = a;
  }
}

// ---------- cosine normalize coords
__global__ void k_norm(const float* __restrict__ c, float* __restrict__ cn){
  int idx = blockIdx.x*256+threadIdx.x;
  if(idx >= 16*350) return;
  float x = c[idx*2], y = c[idx*2+1];
  float n = sqrtf(x*x + y*y);
  float d = fmaxf(n, 1e-12f);
  cn[idx*2] = x/d; cn[idx*2+1] = y/d;
}

// ---------- node mask counts, dtype auto-detected (prefix mask, mask[0]==1 always)
__device__ int mask_mode(const void* p){
  unsigned w0 = ((const unsigned*)p)[0];
  unsigned w1 = ((const unsigned*)p)[1];
  if(w0 == 1u) return (w1 == 0u) ? 4 : 0;
  if(w0 == 0x3F800000u) return 3;
  unsigned short h0 = (unsigned short)(w0 & 0xFFFFu);
  if(h0 == 0x3F80u || h0 == 0x3C00u) return 2;
  return 1;
}
__device__ int mask_get(const void* p, int i, int mode){
  switch(mode){
    case 0: return ((const int*)p)[i] != 0;
    case 1: return ((const unsigned char*)p)[i] != 0;
    case 2: return ((const unsigned short*)p)[i] != 0;
    case 3: return ((const float*)p)[i] != 0.f;
    default: return ((const long long*)p)[i] != 0ll;
  }
}
__global__ void k_counts(const void* __restrict__ masks, int* __restrict__ counts){
  int b = blockIdx.x, tid = threadIdx.x;
  int mode = mask_mode(masks);
  int c = 0;
  for(int i=tid; i<350; i+=64) c += mask_get(masks, b*350+i, mode);
  for(int o=32;o>0;o>>=1) c += __shfl_down(c, o);
  if(tid==0) counts[b] = c;
}

// ---------- pairwise: sim -> 1->32->16->1 MLP -> sigmoid -> mask (f32 out)
__global__ void k_adj(const float* __restrict__ cn, const int* __restrict__ counts,
                      const float* __restrict__ w1, const float* __restrict__ b1,
                      const float* __restrict__ w2, const float* __restrict__ b2,
                      const float* __restrict__ w3, const float* __restrict__ b3,
                      float* __restrict__ out){
  __shared__ float W1[32], B1[32], W2[512], B2[16], W3[16], B3;
  int tid = threadIdx.x;
  if(tid<32){ W1[tid]=w1[tid]; B1[tid]=b1[tid]; }
  for(int t=tid; t<512; t+=256) W2[t]=w2[t];
  if(tid<16){ B2[tid]=b2[tid]; W3[tid]=w3[tid]; }
  if(tid==0) B3=b3[0];
  __syncthreads();
  int idx = blockIdx.x*256+tid;
  if(idx >= 16*350*350) return;
  int m  = idx % 350;
  int t2 = idx / 350;
  int n  = t2 % 350;
  int b  = t2 / 350;
  int cnt = counts[b];
  float o = 0.f;
  if(cnt > 1 && n < cnt && m < cnt){
    float xn = cn[(b*350+n)*2], yn = cn[(b*350+n)*2+1];
    float xm = cn[(b*350+m)*2], ym = cn[(b*350+m)*2+1];
    float s = xn*xm + yn*ym;
    float h1[32];
    #pragma unroll
    for(int k=0;k<32;k++) h1[k] = fmaxf(fmaf(s, W1[k], B1[k]), 0.f);
    float a3 = B3;
    #pragma unroll
    for(int j=0;j<16;j++){
      float t = B2[j];
      #pragma unroll
      for(int k=0;k<32;k++) t = fmaf(h1[k], W2[j*32+k], t);
      a3 = fmaf(fmaxf(t,0.f), W3[j], a3);
    }
    o = 1.f/(1.f + expf(-a3));
  }
  out[idx] = o;
}

extern "C" void kernel_launch(void* const* d_in, const int* in_sizes, int n_in,
                              void* d_out, int out_size, void* d_ws, size_t ws_size,
                              hipStream_t stream){
  const float* images = (const float*)d_in[0];
  const void*  masks  = d_in[1];
  const float *c1w=(const float*)d_in[2],  *c1b=(const float*)d_in[3];
  const float *c2w=(const float*)d_in[4],  *c2b=(const float*)d_in[5];
  const float *c3w=(const float*)d_in[6],  *c3b=(const float*)d_in[7];
  const float *c4w=(const float*)d_in[8],  *c4b=(const float*)d_in[9];
  const float *nd1w=(const float*)d_in[10],*nd1b=(const float*)d_in[11];
  const float *nd2w=(const float*)d_in[12],*nd2b=(const float*)d_in[13];
  const float *cp1w=(const float*)d_in[14],*cp1b=(const float*)d_in[15];
  const float *cp2w=(const float*)d_in[16],*cp2b=(const float*)d_in[17];
  const float *mc1w=(const float*)d_in[18],*mc1b=(const float*)d_in[19];
  const float *mc2w=(const float*)d_in[20],*mc2b=(const float*)d_in[21];
  const float *mc3w=(const float*)d_in[22],*mc3b=(const float*)d_in[23];
  float* out = (float*)d_out;   // f32: coords[11200] | adjacency[1960000] | count[16]

  // ---- workspace (non-overlapping)
  char* W = (char*)d_ws;
  float* feat    = (float*)W;                   // 4096 f32            @0
  float* partial = feat + 4096;                 // 65536 f32 (256 KB)  @16KB
  float* h512    = partial + 65536;             // 8192                @272KB
  float* cn      = h512 + 8192;                 // 11200
  float* h256    = cn + 11200;                  // 4096
  int*   counts  = (int*)(h256 + 4096);         // 16
  bf16*  wt2 = (bf16*)(W + 393216);             // 9*64*32   bf16 (36 KB)   @384KB
  bf16*  wt3 = (bf16*)(W + 458752);             // 9*128*64  bf16 (144 KB)  @448KB
  bf16*  wt4 = (bf16*)(W + 655360);             // 9*256*128 bf16 (576 KB)  @640KB
  bf16*  x1 = (bf16*)(W + 2097152);             // [16][128][128][32] 16.78 MB
  bf16*  x2 = (bf16*)(W + 2097152 + 16777216);  // [16][64][64][64]    8.39 MB
  bf16*  x3 = (bf16*)(W + 2097152);             // [16][32][32][128]   4.19 MB (reuse A)
  bf16*  x4 = (bf16*)(W + 2097152 + 16777216);  // [16][32][32][256]   8.39 MB (reuse B)

  k_wtrans<<<72, 256, 0, stream>>>(c2w, wt2, 64, 32);
  k_wtrans<<<288, 256, 0, stream>>>(c3w, wt3, 128, 64);
  k_wtrans<<<1152, 256, 0, stream>>>(c4w, wt4, 256, 128);

  k_conv1<<<1024, 256, 0, stream>>>(images, c1w, c1b, x1);
  k_convmfma<2><<<1024, 256, 0, stream>>>(x1, wt2, c2b, x2);
  k_convmfma<3><<<512, 256, 0, stream>>>(x2, wt3, c3b, x3);
  k_convmfma<4><<<512, 256, 0, stream>>>(x3, wt4, c4b, x4);
  k_mean1<<<256, 256, 0, stream>>>(x4, partial);
  k_mean2<<<16, 256, 0, stream>>>(partial, feat);

  float* coordsOut = out;
  float* adjOut    = out + 11200;
  float* countOut  = out + 11200 + 1960000;

  k_linw<256><<<2048, 256, 0, stream>>>(feat, nd1w, nd1b, h512, 512, 1);
  k_linw<512><<<2800, 256, 0, stream>>>(h512, nd2w, nd2b, coordsOut, 700, 0);
  k_linw<256><<<1024, 256, 0, stream>>>(feat, cp1w, cp1b, h256, 256, 1);
  k_linw<256><<<4, 256, 0, stream>>>(h256, cp2w, cp2b, countOut, 1, 0);

  k_norm<<<(5600+255)/256, 256, 0, stream>>>(coordsOut, cn);
  k_counts<<<16, 64, 0, stream>>>(masks, counts);
  k_adj<<<(1960000+255)/256, 256, 0, stream>>>(cn, counts, mc1w, mc1b, mc2w, mc2b,
                                               mc3w, mc3b, adjOut);
}